// Round 8
// baseline (102.922 us; speedup 1.0000x reference)
//
#include <hip/hip_runtime.h>

#define LRELU_SLOPE 0.2f

// ---------------- workspace layout (float offsets) ----------------
#define OFF_UV0  0u         // u0[2][128], v0[2][128]           (512)
#define OFF_U1   512u       // u1[2][256]                       (512)
#define OFF_V1   1024u      // v1[2][256]                       (512)
#define OFF_P    1536u      // P[h][g]  (neigh logits, layer1)  (512)
#define OFF_PP   2048u      // P'[h][g] (self  logits, layer1)  (512)
#define OFF_Q    4096u      // Q[2][256][128]                   (65536)
#define OFF_R    69632u     // R[2][256][128]                   (65536)
#define OFF_Y1   135168u    // Y1[10240][256]
#define OFF_Y0   2756608u   // Y0[1024][256]

__device__ __forceinline__ float dot4(float4 a, float4 b) {
    return a.x * b.x + a.y * b.y + a.z * b.z + a.w * b.w;
}

template<int CTRL>
__device__ __forceinline__ float dppmov(float x) {
    return __int_as_float(__builtin_amdgcn_update_dpp(
        0, __float_as_int(x), CTRL, 0xf, 0xf, true));
}
__device__ __forceinline__ float sum16(float x) {
    x += dppmov<0xB1>(x);
    x += dppmov<0x4E>(x);
    x += dppmov<0x141>(x);
    x += dppmov<0x140>(x);
    return x;
}
__device__ __forceinline__ float sum32(float x) {
    x = sum16(x);
    return x + __shfl_xor(x, 16);
}
__device__ __forceinline__ float sum64(float x) {
    float y = sum32(x);
    return y + __shfl_xor(y, 32);
}
__device__ __forceinline__ float lrelu(float x) {
    return (x >= 0.f) ? x : LRELU_SLOPE * x;
}

// ============ prepA: uv0, u1/v1, Q = W1 @ fcW-block ============
__global__ __launch_bounds__(256)
void prepA_kernel(const float* __restrict__ W0, const float* __restrict__ as0,
                  const float* __restrict__ an0,
                  const float* __restrict__ W1, const float* __restrict__ as1,
                  const float* __restrict__ an1,
                  const float* __restrict__ fcW, float* __restrict__ ws) {
    __shared__ float s[32 * 129];
    const int b = blockIdx.x;
    const int t = threadIdx.x;
    if (b < 192) {
        const int wid = b * 4 + (t >> 6);
        const int lane = t & 63;
        const float *wrow, *as, *an;
        if (wid < 256) {
            wrow = W0 + (size_t)wid * 128;
            int h = wid >> 7;
            as = as0 + h * 128; an = an0 + h * 128;
        } else {
            int g = wid - 256;
            wrow = W1 + (size_t)g * 128;
            int h = g >> 8;
            as = as1 + h * 128; an = an1 + h * 128;
        }
        float2 w = *(const float2*)(wrow + 2 * lane);
        float2 sv = *(const float2*)(as + 2 * lane);
        float2 nv = *(const float2*)(an + 2 * lane);
        float au = sum64(w.x * sv.x + w.y * sv.y);
        float av = sum64(w.x * nv.x + w.y * nv.y);
        if (lane == 0) {
            if (wid < 256) { ws[OFF_UV0 + wid] = au; ws[OFF_UV0 + 256 + wid] = av; }
            else { int g = wid - 256; ws[OFF_U1 + g] = au; ws[OFF_V1 + g] = av; }
        }
    } else {
        const int idx = b - 192;
        const int h = idx >> 3, g0 = (idx & 7) * 32;
        const float* Wh = W1 + (size_t)h * 32768;
        for (int ii = t * 4; ii < 32 * 128; ii += 1024) {
            int i = ii >> 7, d = ii & 127;
            float4 g4 = *(const float4*)(Wh + (size_t)(g0 + i) * 128 + d);
            s[i * 129 + d + 0] = g4.x;
            s[i * 129 + d + 1] = g4.y;
            s[i * 129 + d + 2] = g4.z;
            s[i * 129 + d + 3] = g4.w;
        }
        __syncthreads();
        const int dg = t & 31, rg = t >> 5;
        float4 acc[4];
        #pragma unroll
        for (int j = 0; j < 4; ++j) acc[j] = make_float4(0.f, 0.f, 0.f, 0.f);
        const float* fp = fcW + (size_t)h * 16384 + 4 * dg;
        #pragma unroll 4
        for (int d2 = 0; d2 < 128; ++d2) {
            float4 f4 = *(const float4*)(fp + (size_t)d2 * 128);
            #pragma unroll
            for (int j = 0; j < 4; ++j) {
                float x = s[(rg * 4 + j) * 129 + d2];
                acc[j].x += x * f4.x; acc[j].y += x * f4.y;
                acc[j].z += x * f4.z; acc[j].w += x * f4.w;
            }
        }
        float* Qp = ws + OFF_Q + (size_t)h * 32768;
        #pragma unroll
        for (int j = 0; j < 4; ++j)
            *(float4*)(Qp + (size_t)(g0 + rg * 4 + j) * 128 + 4 * dg) = acc[j];
    }
}

// online-softmax update with two rows (one head)
__device__ __forceinline__ void upd2(float& m, float& s, float4& A,
                                     float ea, float eb,
                                     const float4& xa, const float4& xb) {
    float mn = fmaxf(m, fmaxf(ea, eb));
    float sc = __expf(m - mn);
    float pa = __expf(ea - mn);
    float pb = __expf(eb - mn);
    s = s * sc + pa + pb;
    A.x = A.x * sc + pa * xa.x + pb * xb.x;
    A.y = A.y * sc + pa * xa.y + pb * xb.y;
    A.z = A.z * sc + pa * xa.z + pb * xb.z;
    A.w = A.w * sc + pa * xa.w + pb * xb.w;
    m = mn;
}
__device__ __forceinline__ void upd1(float& m, float& s, float4& A,
                                     float ea, const float4& xa) {
    float mn = fmaxf(m, ea);
    float sc = __expf(m - mn);
    float pa = __expf(ea - mn);
    s = s * sc + pa;
    A.x = A.x * sc + pa * xa.x;
    A.y = A.y * sc + pa * xa.y;
    A.z = A.z * sc + pa * xa.z;
    A.w = A.w * sc + pa * xa.w;
    m = mn;
}

// ============ big3: wave-per-target ONLINE-softmax attn (low VGPR) + folds ============
__global__ __launch_bounds__(256)
void big3_kernel(const float* __restrict__ h0, const float* __restrict__ h1,
                 const float* __restrict__ h2, const float* __restrict__ W0,
                 float* __restrict__ ws) {
    const int b = blockIdx.x;
    const int t = threadIdx.x;
    const float* uv0 = ws + OFF_UV0;

    if (b < 2560) {
        // ---- attn25: rows r(i)=2i+half, i<12 pairs; i=12 -> row 24 (half1 dead)
        const int lane = t & 63;
        const int half = lane >> 5;
        const int fl = lane & 31;
        const int m = b * 4 + (t >> 6);
        const float* xnp = h2 + (size_t)m * 3200;
        const float* xsp = h1 + (size_t)m * 128;
        const float4 u0 = *(const float4*)(uv0 + 0 + 4 * fl);
        const float4 u1 = *(const float4*)(uv0 + 128 + 4 * fl);
        const float4 v0 = *(const float4*)(uv0 + 256 + 4 * fl);
        const float4 v1 = *(const float4*)(uv0 + 384 + 4 * fl);

        float4 xs = *(const float4*)(xsp + 4 * fl);
        const float es0 = sum32(dot4(xs, u0));
        const float es1 = sum32(dot4(xs, u1));

        float4 xa = *(const float4*)(xnp + (size_t)(0 + half) * 128 + 4 * fl);
        float4 xb = *(const float4*)(xnp + (size_t)(2 + half) * 128 + 4 * fl);
        float m0 = -1e30f, m1 = -1e30f, s0 = 0.f, s1 = 0.f;
        float4 A0 = make_float4(0.f, 0.f, 0.f, 0.f);
        float4 A1 = make_float4(0.f, 0.f, 0.f, 0.f);
        #pragma unroll
        for (int c = 0; c < 6; ++c) {
            float4 na, nb;
            if (c < 5) {
                na = *(const float4*)(xnp + (size_t)(4 * c + 4 + half) * 128 + 4 * fl);
                nb = *(const float4*)(xnp + (size_t)(4 * c + 6 + half) * 128 + 4 * fl);
            } else {
                na = *(const float4*)(xnp + (size_t)24 * 128 + 4 * fl);
                nb = na;
            }
            float ea0 = lrelu(es0 + sum32(dot4(xa, v0)));
            float ea1 = lrelu(es1 + sum32(dot4(xa, v1)));
            float eb0 = lrelu(es0 + sum32(dot4(xb, v0)));
            float eb1 = lrelu(es1 + sum32(dot4(xb, v1)));
            upd2(m0, s0, A0, ea0, eb0, xa, xb);
            upd2(m1, s1, A1, ea1, eb1, xa, xb);
            xa = na; xb = nb;
        }
        {   // tail: row 24 (half0 real, half1 dead)
            float e0 = lrelu(es0 + sum32(dot4(xa, v0)));
            float e1 = lrelu(es1 + sum32(dot4(xa, v1)));
            if (half) { e0 = -1e30f; e1 = -1e30f; }
            upd1(m0, s0, A0, e0, xa);
            upd1(m1, s1, A1, e1, xa);
        }
        // cross-half merge
        float g0 = fmaxf(m0, __shfl_xor(m0, 32));
        float g1 = fmaxf(m1, __shfl_xor(m1, 32));
        float c0 = __expf(m0 - g0), c1 = __expf(m1 - g1);
        s0 *= c0; s1 *= c1;
        A0.x *= c0; A0.y *= c0; A0.z *= c0; A0.w *= c0;
        A1.x *= c1; A1.y *= c1; A1.z *= c1; A1.w *= c1;
        s0 += __shfl_xor(s0, 32); s1 += __shfl_xor(s1, 32);
        A0.x += __shfl_xor(A0.x, 32); A0.y += __shfl_xor(A0.y, 32);
        A0.z += __shfl_xor(A0.z, 32); A0.w += __shfl_xor(A0.w, 32);
        A1.x += __shfl_xor(A1.x, 32); A1.y += __shfl_xor(A1.y, 32);
        A1.z += __shfl_xor(A1.z, 32); A1.w += __shfl_xor(A1.w, 32);
        const float inv = 1.f / (half ? s1 : s0);
        const float4 S = half ? A1 : A0;
        float4 o;
        o.x = S.x * inv; o.y = S.y * inv; o.z = S.z * inv; o.w = S.w * inv;
        *(float4*)(ws + OFF_Y1 + (size_t)m * 256 + half * 128 + 4 * fl) = o;
    } else if (b < 2816) {
        // ---- attn10: rows r(i)=2i+half, i in [0,4]; all rows valid
        const int lane = t & 63;
        const int half = lane >> 5;
        const int fl = lane & 31;
        const int m = (b - 2560) * 4 + (t >> 6);
        const float* xnp = h1 + (size_t)m * 1280;
        const float* xsp = h0 + (size_t)m * 128;
        const float4 u0 = *(const float4*)(uv0 + 0 + 4 * fl);
        const float4 u1 = *(const float4*)(uv0 + 128 + 4 * fl);
        const float4 v0 = *(const float4*)(uv0 + 256 + 4 * fl);
        const float4 v1 = *(const float4*)(uv0 + 384 + 4 * fl);

        float4 xs = *(const float4*)(xsp + 4 * fl);
        const float es0 = sum32(dot4(xs, u0));
        const float es1 = sum32(dot4(xs, u1));

        float4 xa = *(const float4*)(xnp + (size_t)(0 + half) * 128 + 4 * fl);
        float4 xb = *(const float4*)(xnp + (size_t)(2 + half) * 128 + 4 * fl);
        float m0 = -1e30f, m1 = -1e30f, s0 = 0.f, s1 = 0.f;
        float4 A0 = make_float4(0.f, 0.f, 0.f, 0.f);
        float4 A1 = make_float4(0.f, 0.f, 0.f, 0.f);
        #pragma unroll
        for (int c = 0; c < 2; ++c) {
            float4 na, nb;
            if (c < 1) {
                na = *(const float4*)(xnp + (size_t)(4 + half) * 128 + 4 * fl);
                nb = *(const float4*)(xnp + (size_t)(6 + half) * 128 + 4 * fl);
            } else {
                na = *(const float4*)(xnp + (size_t)(8 + half) * 128 + 4 * fl);
                nb = na;
            }
            float ea0 = lrelu(es0 + sum32(dot4(xa, v0)));
            float ea1 = lrelu(es1 + sum32(dot4(xa, v1)));
            float eb0 = lrelu(es0 + sum32(dot4(xb, v0)));
            float eb1 = lrelu(es1 + sum32(dot4(xb, v1)));
            upd2(m0, s0, A0, ea0, eb0, xa, xb);
            upd2(m1, s1, A1, ea1, eb1, xa, xb);
            xa = na; xb = nb;
        }
        {   // tail: rows 8+half (valid both halves)
            float e0 = lrelu(es0 + sum32(dot4(xa, v0)));
            float e1 = lrelu(es1 + sum32(dot4(xa, v1)));
            upd1(m0, s0, A0, e0, xa);
            upd1(m1, s1, A1, e1, xa);
        }
        float g0 = fmaxf(m0, __shfl_xor(m0, 32));
        float g1 = fmaxf(m1, __shfl_xor(m1, 32));
        float c0 = __expf(m0 - g0), c1 = __expf(m1 - g1);
        s0 *= c0; s1 *= c1;
        A0.x *= c0; A0.y *= c0; A0.z *= c0; A0.w *= c0;
        A1.x *= c1; A1.y *= c1; A1.z *= c1; A1.w *= c1;
        s0 += __shfl_xor(s0, 32); s1 += __shfl_xor(s1, 32);
        A0.x += __shfl_xor(A0.x, 32); A0.y += __shfl_xor(A0.y, 32);
        A0.z += __shfl_xor(A0.z, 32); A0.w += __shfl_xor(A0.w, 32);
        A1.x += __shfl_xor(A1.x, 32); A1.y += __shfl_xor(A1.y, 32);
        A1.z += __shfl_xor(A1.z, 32); A1.w += __shfl_xor(A1.w, 32);
        const float inv = 1.f / (half ? s1 : s0);
        const float4 S = half ? A1 : A0;
        float4 o;
        o.x = S.x * inv; o.y = S.y * inv; o.z = S.z * inv; o.w = S.w * inv;
        *(float4*)(ws + OFF_Y0 + (size_t)m * 256 + half * 128 + 4 * fl) = o;
    } else if (b < 2944) {
        // ---- P/P' folds
        const int wid = (b - 2816) * 4 + (t >> 6);
        const int lane = t & 63;
        const int h = wid >> 8, rest = wid & 255;
        const int h0i = rest >> 7;
        const float* wrow = W0 + (size_t)rest * 128;
        float2 w2 = *(const float2*)(wrow + 2 * lane);
        float2 su = *(const float2*)(ws + OFF_U1 + h * 256 + h0i * 128 + 2 * lane);
        float2 sv = *(const float2*)(ws + OFF_V1 + h * 256 + h0i * 128 + 2 * lane);
        float pu = sum64(w2.x * su.x + w2.y * su.y);
        float pv = sum64(w2.x * sv.x + w2.y * sv.y);
        if (lane == 0) { ws[OFF_PP + wid] = pu; ws[OFF_P + wid] = pv; }
    } else {
        // ---- R tiles
        __shared__ float smem[4160];
        const int idx = b - 2944;
        const int h = idx >> 3;
        const int h0i = (idx >> 2) & 1;
        const int f0 = (idx & 3) * 32;
        const float* W0h = W0 + (size_t)h0i * 16384;
        for (int ii = t * 4; ii < 32 * 128; ii += 1024) {
            int i = ii >> 7, d = ii & 127;
            float4 g4 = *(const float4*)(W0h + (size_t)(f0 + i) * 128 + d);
            smem[i * 129 + d + 0] = g4.x;
            smem[i * 129 + d + 1] = g4.y;
            smem[i * 129 + d + 2] = g4.z;
            smem[i * 129 + d + 3] = g4.w;
        }
        __syncthreads();
        const int dg = t & 31, rg = t >> 5;
        float4 acc[4];
        #pragma unroll
        for (int j = 0; j < 4; ++j) acc[j] = make_float4(0.f, 0.f, 0.f, 0.f);
        const float* Qp = ws + OFF_Q + (size_t)h * 32768 + (size_t)h0i * 16384 + 4 * dg;
        #pragma unroll 4
        for (int d = 0; d < 128; ++d) {
            float4 q4 = *(const float4*)(Qp + (size_t)d * 128);
            #pragma unroll
            for (int j = 0; j < 4; ++j) {
                float x = smem[(rg * 4 + j) * 129 + d];
                acc[j].x += x * q4.x; acc[j].y += x * q4.y;
                acc[j].z += x * q4.z; acc[j].w += x * q4.w;
            }
        }
        float* Rp = ws + OFF_R + (size_t)h * 32768 + (size_t)h0i * 16384;
        #pragma unroll
        for (int j = 0; j < 4; ++j)
            *(float4*)(Rp + (size_t)(f0 + rg * 4 + j) * 128 + 4 * dg) = acc[j];
    }
}

// ============ FINAL: layer1 attn via P/P' + out = ybar @ R ============
__global__ __launch_bounds__(256)
void final_kernel(const float* __restrict__ ws, float* __restrict__ out) {
    __shared__ float xn[22 * 256];
    __shared__ float yb[1024];
    __shared__ float pr[2][2][128];
    __shared__ float en[2][11][2];
    __shared__ float al[2][10][2];
    const int t = threadIdx.x;
    const int m0 = blockIdx.x * 2;
    const int rlane = t & 63;
    const int rg = t >> 6;
    const float* P  = ws + OFF_P;
    const float* Pp = ws + OFF_PP;
    const float* Y1 = ws + OFF_Y1;
    const float* Y0 = ws + OFF_Y0;
    const float4 su0 = *(const float4*)(Pp + 0 + 4 * rlane);
    const float4 su1 = *(const float4*)(Pp + 256 + 4 * rlane);
    const float4 nv0 = *(const float4*)(P + 0 + 4 * rlane);
    const float4 nv1 = *(const float4*)(P + 256 + 4 * rlane);
    float4 g[6];
    #pragma unroll
    for (int i = 0; i < 6; ++i) {
        int rho = rg + 4 * i;
        if (rho < 22) {
            int r = rho / 11, k = rho % 11;
            int m = m0 + r;
            const float* src = (k < 10) ? (Y1 + ((size_t)m * 10 + k) * 256)
                                        : (Y0 + (size_t)m * 256);
            g[i] = *(const float4*)(src + 4 * rlane);
        }
    }
    #pragma unroll
    for (int i = 0; i < 6; ++i) {
        int rho = rg + 4 * i;
        if (rho < 22) {
            int r = rho / 11, k = rho % 11;
            *(float4*)(&xn[rho * 256 + 4 * rlane]) = g[i];
            float p0 = sum64(dot4(g[i], (k < 10) ? nv0 : su0));
            float p1 = sum64(dot4(g[i], (k < 10) ? nv1 : su1));
            if (rlane == 0) { en[r][k][0] = p0; en[r][k][1] = p1; }
        }
    }
    __syncthreads();
    if (t < 128) {
        int r = t >> 6, h = (t >> 5) & 1, k = t & 31;
        float e = -1e30f;
        if (k < 10) {
            float z = en[r][10][h] + en[r][k][h];
            e = (z >= 0.f) ? z : LRELU_SLOPE * z;
        }
        float mx = e;
        #pragma unroll
        for (int off = 16; off > 0; off >>= 1) mx = fmaxf(mx, __shfl_xor(mx, off));
        float ex = (k < 10) ? __expf(e - mx) : 0.f;
        float sm = ex;
        #pragma unroll
        for (int off = 16; off > 0; off >>= 1) sm += __shfl_xor(sm, off);
        if (k < 10) al[r][k][h] = ex / sm;
    }
    __syncthreads();
    #pragma unroll
    for (int i = 0; i < 4; ++i) {
        int c = t + 256 * i;
        int r = c >> 9, rem = c & 511, h = rem >> 8, f = rem & 255;
        float acc = 0.f;
        #pragma unroll
        for (int k = 0; k < 10; ++k) acc += al[r][k][h] * xn[(r * 11 + k) * 256 + f];
        yb[c] = acc;
    }
    __syncthreads();
    {
        const int seg = t >> 7;
        const int o = t & 127;
        const float* Rv = ws + OFF_R + (size_t)seg * 256 * 128 + o;
        const float* y0p = yb + seg * 256;
        const float* y1p = yb + 512 + seg * 256;
        float a0 = 0.f, a1 = 0.f;
        #pragma unroll 8
        for (int gi = 0; gi < 256; ++gi) {
            float rv = Rv[(size_t)gi * 128];
            a0 += y0p[gi] * rv;
            a1 += y1p[gi] * rv;
        }
        pr[seg][0][o] = a0;
        pr[seg][1][o] = a1;
    }
    __syncthreads();
    {
        const int r = t >> 7, o = t & 127;
        out[(size_t)(m0 + r) * 128 + o] = pr[0][r][o] + pr[1][r][o];
    }
}

extern "C" void kernel_launch(void* const* d_in, const int* in_sizes, int n_in,
                              void* d_out, int out_size, void* d_ws, size_t ws_size,
                              hipStream_t stream) {
    const float* h0  = (const float*)d_in[0];
    const float* h1  = (const float*)d_in[1];
    const float* h2  = (const float*)d_in[2];
    const float* W0  = (const float*)d_in[3];
    const float* as0 = (const float*)d_in[4];
    const float* an0 = (const float*)d_in[5];
    const float* W1  = (const float*)d_in[6];
    const float* as1 = (const float*)d_in[7];
    const float* an1 = (const float*)d_in[8];
    const float* fcW = (const float*)d_in[9];
    float* outp = (float*)d_out;
    float* ws = (float*)d_ws;

    hipLaunchKernelGGL(prepA_kernel, dim3(208), dim3(256), 0, stream,
                       W0, as0, an0, W1, as1, an1, fcW, ws);
    // ATTRIBUTION PROBE: big3 launched TWICE (idempotent — identical writes).
    // dur_us(R8) - dur_us(R7) = true duration of big3.
    hipLaunchKernelGGL(big3_kernel, dim3(2960), dim3(256), 0, stream,
                       h0, h1, h2, W0, ws);
    hipLaunchKernelGGL(big3_kernel, dim3(2960), dim3(256), 0, stream,
                       h0, h1, h2, W0, ws);
    hipLaunchKernelGGL(final_kernel, dim3(512), dim3(256), 0, stream,
                       ws, outp);
}

// Round 9
// 63.669 us; speedup vs baseline: 1.6165x; 1.6165x over previous
//
#include <hip/hip_runtime.h>

#define LRELU_SLOPE 0.2f

// ---------------- workspace layout (float offsets) ----------------
#define OFF_UV0  0u         // u0[2][128], v0[2][128]           (512)
#define OFF_U1   512u       // u1[2][256]                       (512)
#define OFF_V1   1024u      // v1[2][256]                       (512)
#define OFF_P    1536u      // P[h][g]  (neigh logits, layer1)  (512)
#define OFF_PP   2048u      // P'[h][g] (self  logits, layer1)  (512)
#define OFF_Q    4096u      // Q[2][256][128]                   (65536)
#define OFF_R    69632u     // R[2][256][128]                   (65536)
#define OFF_Y1   135168u    // Y1[10240][256]
#define OFF_Y0   2756608u   // Y0[1024][256]

__device__ __forceinline__ float dot4(float4 a, float4 b) {
    return a.x * b.x + a.y * b.y + a.z * b.z + a.w * b.w;
}

template<int CTRL>
__device__ __forceinline__ float dppmov(float x) {
    return __int_as_float(__builtin_amdgcn_update_dpp(
        0, __float_as_int(x), CTRL, 0xf, 0xf, true));
}
__device__ __forceinline__ float sum16(float x) {
    x += dppmov<0xB1>(x);
    x += dppmov<0x4E>(x);
    x += dppmov<0x141>(x);
    x += dppmov<0x140>(x);
    return x;
}
__device__ __forceinline__ float sum32(float x) {
    x = sum16(x);
    return x + __shfl_xor(x, 16);   // stays within each 32-lane half
}
__device__ __forceinline__ float sum64(float x) {
    float y = sum32(x);
    return y + __shfl_xor(y, 32);
}
__device__ __forceinline__ float lrelu(float x) {
    return (x >= 0.f) ? x : LRELU_SLOPE * x;
}

// ============ prepA: uv0, u1/v1, Q = W1 @ fcW-block (Q on 32 blocks) ============
__global__ __launch_bounds__(256)
void prepA_kernel(const float* __restrict__ W0, const float* __restrict__ as0,
                  const float* __restrict__ an0,
                  const float* __restrict__ W1, const float* __restrict__ as1,
                  const float* __restrict__ an1,
                  const float* __restrict__ fcW, float* __restrict__ ws) {
    __shared__ float s[16 * 129];
    const int b = blockIdx.x;
    const int t = threadIdx.x;
    if (b < 192) {
        const int wid = b * 4 + (t >> 6);
        const int lane = t & 63;
        const float *wrow, *as, *an;
        if (wid < 256) {
            wrow = W0 + (size_t)wid * 128;
            int h = wid >> 7;
            as = as0 + h * 128; an = an0 + h * 128;
        } else {
            int g = wid - 256;
            wrow = W1 + (size_t)g * 128;
            int h = g >> 8;
            as = as1 + h * 128; an = an1 + h * 128;
        }
        float2 w = *(const float2*)(wrow + 2 * lane);
        float2 sv = *(const float2*)(as + 2 * lane);
        float2 nv = *(const float2*)(an + 2 * lane);
        float au = sum64(w.x * sv.x + w.y * sv.y);
        float av = sum64(w.x * nv.x + w.y * nv.y);
        if (lane == 0) {
            if (wid < 256) { ws[OFF_UV0 + wid] = au; ws[OFF_UV0 + 256 + wid] = av; }
            else { int g = wid - 256; ws[OFF_U1 + g] = au; ws[OFF_V1 + g] = av; }
        }
    } else {
        // Q[h][g][o] = sum_d2 W1[h][g][d2] * fcW[h*128+d2][o]; 32 tiles of 16 rows
        const int idx = b - 192;
        const int h = idx >> 4, g0 = (idx & 15) * 16;
        const float* Wh = W1 + (size_t)h * 32768;
        for (int ii = t * 4; ii < 16 * 128; ii += 1024) {
            int i = ii >> 7, d = ii & 127;
            float4 g4 = *(const float4*)(Wh + (size_t)(g0 + i) * 128 + d);
            s[i * 129 + d + 0] = g4.x;
            s[i * 129 + d + 1] = g4.y;
            s[i * 129 + d + 2] = g4.z;
            s[i * 129 + d + 3] = g4.w;
        }
        __syncthreads();
        const int dg = t & 31, rg = t >> 5;     // 8 row-groups x 2 rows
        float4 acc[2];
        acc[0] = make_float4(0.f, 0.f, 0.f, 0.f);
        acc[1] = make_float4(0.f, 0.f, 0.f, 0.f);
        const float* fp = fcW + (size_t)h * 16384 + 4 * dg;
        #pragma unroll 4
        for (int d2 = 0; d2 < 128; ++d2) {
            float4 f4 = *(const float4*)(fp + (size_t)d2 * 128);
            #pragma unroll
            for (int j = 0; j < 2; ++j) {
                float x = s[(rg * 2 + j) * 129 + d2];
                acc[j].x += x * f4.x; acc[j].y += x * f4.y;
                acc[j].z += x * f4.z; acc[j].w += x * f4.w;
            }
        }
        float* Qp = ws + OFF_Q + (size_t)h * 32768;
        #pragma unroll
        for (int j = 0; j < 2; ++j)
            *(float4*)(Qp + (size_t)(g0 + rg * 2 + j) * 128 + 4 * dg) = acc[j];
    }
}

// online-softmax updates
__device__ __forceinline__ void upd2(float& m, float& s, float4& A,
                                     float ea, float eb,
                                     const float4& xa, const float4& xb) {
    float mn = fmaxf(m, fmaxf(ea, eb));
    float sc = __expf(m - mn);
    float pa = __expf(ea - mn);
    float pb = __expf(eb - mn);
    s = s * sc + pa + pb;
    A.x = A.x * sc + pa * xa.x + pb * xb.x;
    A.y = A.y * sc + pa * xa.y + pb * xb.y;
    A.z = A.z * sc + pa * xa.z + pb * xb.z;
    A.w = A.w * sc + pa * xa.w + pb * xb.w;
    m = mn;
}
__device__ __forceinline__ void upd1(float& m, float& s, float4& A,
                                     float ea, const float4& xa) {
    float mn = fmaxf(m, ea);
    float sc = __expf(m - mn);
    float pa = __expf(ea - mn);
    s = s * sc + pa;
    A.x = A.x * sc + pa * xa.x;
    A.y = A.y * sc + pa * xa.y;
    A.z = A.z * sc + pa * xa.z;
    A.w = A.w * sc + pa * xa.w;
    m = mn;
}

// ============ big4: TWO targets per wave (32-lane halves), single residency gen ============
// blocks: [0,1280) attn25 (8 targets/blk) | [1280,1408) attn10 | [1408,1536) P/P' | [1536,1552) R
__global__ __launch_bounds__(256)
void big4_kernel(const float* __restrict__ h0, const float* __restrict__ h1,
                 const float* __restrict__ h2, const float* __restrict__ W0,
                 float* __restrict__ ws) {
    const int b = blockIdx.x;
    const int t = threadIdx.x;
    const float* uv0 = ws + OFF_UV0;

    if (b < 1280) {
        // ---- attn25: each 32-lane half owns one target; all reductions sum32
        const int lane = t & 63;
        const int sub = lane >> 5;
        const int fl = lane & 31;
        const int m = (b * 4 + (t >> 6)) * 2 + sub;
        const float* xnp = h2 + (size_t)m * 3200;
        const float* xsp = h1 + (size_t)m * 128;
        const float4 u0 = *(const float4*)(uv0 + 0 + 4 * fl);
        const float4 u1 = *(const float4*)(uv0 + 128 + 4 * fl);
        const float4 v0 = *(const float4*)(uv0 + 256 + 4 * fl);
        const float4 v1 = *(const float4*)(uv0 + 384 + 4 * fl);

        float4 xs = *(const float4*)(xsp + 4 * fl);
        const float es0 = sum32(dot4(xs, u0));
        const float es1 = sum32(dot4(xs, u1));

        float4 xa = *(const float4*)(xnp + 4 * fl);
        float4 xb = *(const float4*)(xnp + 128 + 4 * fl);
        float m0 = -1e30f, m1 = -1e30f, s0 = 0.f, s1 = 0.f;
        float4 A0 = make_float4(0.f, 0.f, 0.f, 0.f);
        float4 A1 = make_float4(0.f, 0.f, 0.f, 0.f);
        #pragma unroll
        for (int c = 0; c < 12; ++c) {
            float4 na, nb;
            if (c < 11) {
                na = *(const float4*)(xnp + (size_t)(2 * c + 2) * 128 + 4 * fl);
                nb = *(const float4*)(xnp + (size_t)(2 * c + 3) * 128 + 4 * fl);
            } else {
                na = *(const float4*)(xnp + (size_t)24 * 128 + 4 * fl);
                nb = na;
            }
            float ea0 = lrelu(es0 + sum32(dot4(xa, v0)));
            float ea1 = lrelu(es1 + sum32(dot4(xa, v1)));
            float eb0 = lrelu(es0 + sum32(dot4(xb, v0)));
            float eb1 = lrelu(es1 + sum32(dot4(xb, v1)));
            upd2(m0, s0, A0, ea0, eb0, xa, xb);
            upd2(m1, s1, A1, ea1, eb1, xa, xb);
            xa = na; xb = nb;
        }
        {   // tail: row 24
            float e0 = lrelu(es0 + sum32(dot4(xa, v0)));
            float e1 = lrelu(es1 + sum32(dot4(xa, v1)));
            upd1(m0, s0, A0, e0, xa);
            upd1(m1, s1, A1, e1, xa);
        }
        const float i0 = 1.f / s0, i1 = 1.f / s1;
        float4 o0, o1;
        o0.x = A0.x * i0; o0.y = A0.y * i0; o0.z = A0.z * i0; o0.w = A0.w * i0;
        o1.x = A1.x * i1; o1.y = A1.y * i1; o1.z = A1.z * i1; o1.w = A1.w * i1;
        *(float4*)(ws + OFF_Y1 + (size_t)m * 256 + 4 * fl) = o0;
        *(float4*)(ws + OFF_Y1 + (size_t)m * 256 + 128 + 4 * fl) = o1;
    } else if (b < 1408) {
        // ---- attn10: two targets per wave
        const int lane = t & 63;
        const int sub = lane >> 5;
        const int fl = lane & 31;
        const int m = ((b - 1280) * 4 + (t >> 6)) * 2 + sub;
        const float* xnp = h1 + (size_t)m * 1280;
        const float* xsp = h0 + (size_t)m * 128;
        const float4 u0 = *(const float4*)(uv0 + 0 + 4 * fl);
        const float4 u1 = *(const float4*)(uv0 + 128 + 4 * fl);
        const float4 v0 = *(const float4*)(uv0 + 256 + 4 * fl);
        const float4 v1 = *(const float4*)(uv0 + 384 + 4 * fl);

        float4 xs = *(const float4*)(xsp + 4 * fl);
        const float es0 = sum32(dot4(xs, u0));
        const float es1 = sum32(dot4(xs, u1));

        float4 xa = *(const float4*)(xnp + 4 * fl);
        float4 xb = *(const float4*)(xnp + 128 + 4 * fl);
        float m0 = -1e30f, m1 = -1e30f, s0 = 0.f, s1 = 0.f;
        float4 A0 = make_float4(0.f, 0.f, 0.f, 0.f);
        float4 A1 = make_float4(0.f, 0.f, 0.f, 0.f);
        #pragma unroll
        for (int c = 0; c < 5; ++c) {
            float4 na, nb;
            if (c < 4) {
                na = *(const float4*)(xnp + (size_t)(2 * c + 2) * 128 + 4 * fl);
                nb = *(const float4*)(xnp + (size_t)(2 * c + 3) * 128 + 4 * fl);
            } else {
                na = xa; nb = xb;   // unused
            }
            float ea0 = lrelu(es0 + sum32(dot4(xa, v0)));
            float ea1 = lrelu(es1 + sum32(dot4(xa, v1)));
            float eb0 = lrelu(es0 + sum32(dot4(xb, v0)));
            float eb1 = lrelu(es1 + sum32(dot4(xb, v1)));
            upd2(m0, s0, A0, ea0, eb0, xa, xb);
            upd2(m1, s1, A1, ea1, eb1, xa, xb);
            xa = na; xb = nb;
        }
        const float i0 = 1.f / s0, i1 = 1.f / s1;
        float4 o0, o1;
        o0.x = A0.x * i0; o0.y = A0.y * i0; o0.z = A0.z * i0; o0.w = A0.w * i0;
        o1.x = A1.x * i1; o1.y = A1.y * i1; o1.z = A1.z * i1; o1.w = A1.w * i1;
        *(float4*)(ws + OFF_Y0 + (size_t)m * 256 + 4 * fl) = o0;
        *(float4*)(ws + OFF_Y0 + (size_t)m * 256 + 128 + 4 * fl) = o1;
    } else if (b < 1536) {
        // ---- P/P' folds
        const int wid = (b - 1408) * 4 + (t >> 6);
        const int lane = t & 63;
        const int h = wid >> 8, rest = wid & 255;
        const int h0i = rest >> 7;
        const float* wrow = W0 + (size_t)rest * 128;
        float2 w2 = *(const float2*)(wrow + 2 * lane);
        float2 su = *(const float2*)(ws + OFF_U1 + h * 256 + h0i * 128 + 2 * lane);
        float2 sv = *(const float2*)(ws + OFF_V1 + h * 256 + h0i * 128 + 2 * lane);
        float pu = sum64(w2.x * su.x + w2.y * su.y);
        float pv = sum64(w2.x * sv.x + w2.y * sv.y);
        if (lane == 0) { ws[OFF_PP + wid] = pu; ws[OFF_P + wid] = pv; }
    } else {
        // ---- R tiles
        __shared__ float smem[4160];
        const int idx = b - 1536;
        const int h = idx >> 3;
        const int h0i = (idx >> 2) & 1;
        const int f0 = (idx & 3) * 32;
        const float* W0h = W0 + (size_t)h0i * 16384;
        for (int ii = t * 4; ii < 32 * 128; ii += 1024) {
            int i = ii >> 7, d = ii & 127;
            float4 g4 = *(const float4*)(W0h + (size_t)(f0 + i) * 128 + d);
            smem[i * 129 + d + 0] = g4.x;
            smem[i * 129 + d + 1] = g4.y;
            smem[i * 129 + d + 2] = g4.z;
            smem[i * 129 + d + 3] = g4.w;
        }
        __syncthreads();
        const int dg = t & 31, rg = t >> 5;
        float4 acc[4];
        #pragma unroll
        for (int j = 0; j < 4; ++j) acc[j] = make_float4(0.f, 0.f, 0.f, 0.f);
        const float* Qp = ws + OFF_Q + (size_t)h * 32768 + (size_t)h0i * 16384 + 4 * dg;
        #pragma unroll 4
        for (int d = 0; d < 128; ++d) {
            float4 q4 = *(const float4*)(Qp + (size_t)d * 128);
            #pragma unroll
            for (int j = 0; j < 4; ++j) {
                float x = smem[(rg * 4 + j) * 129 + d];
                acc[j].x += x * q4.x; acc[j].y += x * q4.y;
                acc[j].z += x * q4.z; acc[j].w += x * q4.w;
            }
        }
        float* Rp = ws + OFF_R + (size_t)h * 32768 + (size_t)h0i * 16384;
        #pragma unroll
        for (int j = 0; j < 4; ++j)
            *(float4*)(Rp + (size_t)(f0 + rg * 4 + j) * 128 + 4 * dg) = acc[j];
    }
}

// ============ FINAL: layer1 attn via P/P' + out = ybar @ R (unchanged R7) ============
__global__ __launch_bounds__(256)
void final_kernel(const float* __restrict__ ws, float* __restrict__ out) {
    __shared__ float xn[22 * 256];
    __shared__ float yb[1024];
    __shared__ float pr[2][2][128];
    __shared__ float en[2][11][2];
    __shared__ float al[2][10][2];
    const int t = threadIdx.x;
    const int m0 = blockIdx.x * 2;
    const int rlane = t & 63;
    const int rg = t >> 6;
    const float* P  = ws + OFF_P;
    const float* Pp = ws + OFF_PP;
    const float* Y1 = ws + OFF_Y1;
    const float* Y0 = ws + OFF_Y0;
    const float4 su0 = *(const float4*)(Pp + 0 + 4 * rlane);
    const float4 su1 = *(const float4*)(Pp + 256 + 4 * rlane);
    const float4 nv0 = *(const float4*)(P + 0 + 4 * rlane);
    const float4 nv1 = *(const float4*)(P + 256 + 4 * rlane);
    float4 g[6];
    #pragma unroll
    for (int i = 0; i < 6; ++i) {
        int rho = rg + 4 * i;
        if (rho < 22) {
            int r = rho / 11, k = rho % 11;
            int m = m0 + r;
            const float* src = (k < 10) ? (Y1 + ((size_t)m * 10 + k) * 256)
                                        : (Y0 + (size_t)m * 256);
            g[i] = *(const float4*)(src + 4 * rlane);
        }
    }
    #pragma unroll
    for (int i = 0; i < 6; ++i) {
        int rho = rg + 4 * i;
        if (rho < 22) {
            int r = rho / 11, k = rho % 11;
            *(float4*)(&xn[rho * 256 + 4 * rlane]) = g[i];
            float p0 = sum64(dot4(g[i], (k < 10) ? nv0 : su0));
            float p1 = sum64(dot4(g[i], (k < 10) ? nv1 : su1));
            if (rlane == 0) { en[r][k][0] = p0; en[r][k][1] = p1; }
        }
    }
    __syncthreads();
    if (t < 128) {
        int r = t >> 6, h = (t >> 5) & 1, k = t & 31;
        float e = -1e30f;
        if (k < 10) {
            float z = en[r][10][h] + en[r][k][h];
            e = (z >= 0.f) ? z : LRELU_SLOPE * z;
        }
        float mx = e;
        #pragma unroll
        for (int off = 16; off > 0; off >>= 1) mx = fmaxf(mx, __shfl_xor(mx, off));
        float ex = (k < 10) ? __expf(e - mx) : 0.f;
        float sm = ex;
        #pragma unroll
        for (int off = 16; off > 0; off >>= 1) sm += __shfl_xor(sm, off);
        if (k < 10) al[r][k][h] = ex / sm;
    }
    __syncthreads();
    #pragma unroll
    for (int i = 0; i < 4; ++i) {
        int c = t + 256 * i;
        int r = c >> 9, rem = c & 511, h = rem >> 8, f = rem & 255;
        float acc = 0.f;
        #pragma unroll
        for (int k = 0; k < 10; ++k) acc += al[r][k][h] * xn[(r * 11 + k) * 256 + f];
        yb[c] = acc;
    }
    __syncthreads();
    {
        const int seg = t >> 7;
        const int o = t & 127;
        const float* Rv = ws + OFF_R + (size_t)seg * 256 * 128 + o;
        const float* y0p = yb + seg * 256;
        const float* y1p = yb + 512 + seg * 256;
        float a0 = 0.f, a1 = 0.f;
        #pragma unroll 8
        for (int gi = 0; gi < 256; ++gi) {
            float rv = Rv[(size_t)gi * 128];
            a0 += y0p[gi] * rv;
            a1 += y1p[gi] * rv;
        }
        pr[seg][0][o] = a0;
        pr[seg][1][o] = a1;
    }
    __syncthreads();
    {
        const int r = t >> 7, o = t & 127;
        out[(size_t)(m0 + r) * 128 + o] = pr[0][r][o] + pr[1][r][o];
    }
}

extern "C" void kernel_launch(void* const* d_in, const int* in_sizes, int n_in,
                              void* d_out, int out_size, void* d_ws, size_t ws_size,
                              hipStream_t stream) {
    const float* h0  = (const float*)d_in[0];
    const float* h1  = (const float*)d_in[1];
    const float* h2  = (const float*)d_in[2];
    const float* W0  = (const float*)d_in[3];
    const float* as0 = (const float*)d_in[4];
    const float* an0 = (const float*)d_in[5];
    const float* W1  = (const float*)d_in[6];
    const float* as1 = (const float*)d_in[7];
    const float* an1 = (const float*)d_in[8];
    const float* fcW = (const float*)d_in[9];
    float* outp = (float*)d_out;
    float* ws = (float*)d_ws;

    hipLaunchKernelGGL(prepA_kernel, dim3(224), dim3(256), 0, stream,
                       W0, as0, an0, W1, as1, an1, fcW, ws);
    hipLaunchKernelGGL(big4_kernel, dim3(1552), dim3(256), 0, stream,
                       h0, h1, h2, W0, ws);
    hipLaunchKernelGGL(final_kernel, dim3(512), dim3(256), 0, stream,
                       ws, outp);
}

// Round 10
// 60.808 us; speedup vs baseline: 1.6926x; 1.0470x over previous
//
#include <hip/hip_runtime.h>

#define LRELU_SLOPE 0.2f

// ---------------- workspace layout (float offsets) ----------------
#define OFF_UV0  0u         // u0[2][128], v0[2][128]           (512)
#define OFF_U1   512u       // u1[2][256]                       (512)
#define OFF_V1   1024u      // v1[2][256]                       (512)
#define OFF_P    1536u      // P[h][g]  (neigh logits, layer1)  (512)
#define OFF_PP   2048u      // P'[h][g] (self  logits, layer1)  (512)
#define OFF_Q    4096u      // Q[2][256][128]                   (65536)
#define OFF_R    69632u     // R[2][256][128]                   (65536)
#define OFF_Y1   135168u    // Y1[10240][256]
#define OFF_Y0   2756608u   // Y0[1024][256]

__device__ __forceinline__ float dot4(float4 a, float4 b) {
    return a.x * b.x + a.y * b.y + a.z * b.z + a.w * b.w;
}

template<int CTRL>
__device__ __forceinline__ float dppmov(float x) {
    return __int_as_float(__builtin_amdgcn_update_dpp(
        0, __float_as_int(x), CTRL, 0xf, 0xf, true));
}
__device__ __forceinline__ float sum16(float x) {
    x += dppmov<0xB1>(x);
    x += dppmov<0x4E>(x);
    x += dppmov<0x141>(x);
    x += dppmov<0x140>(x);
    return x;
}
__device__ __forceinline__ float sum32(float x) {
    x = sum16(x);
    return x + __shfl_xor(x, 16);
}
__device__ __forceinline__ float sum64(float x) {
    float y = sum32(x);
    return y + __shfl_xor(y, 32);
}
__device__ __forceinline__ float lrelu(float x) {
    return (x >= 0.f) ? x : LRELU_SLOPE * x;
}

// ============ prepA: uv0, u1/v1, Q = W1 @ fcW-block (unchanged R9) ============
__global__ __launch_bounds__(256)
void prepA_kernel(const float* __restrict__ W0, const float* __restrict__ as0,
                  const float* __restrict__ an0,
                  const float* __restrict__ W1, const float* __restrict__ as1,
                  const float* __restrict__ an1,
                  const float* __restrict__ fcW, float* __restrict__ ws) {
    __shared__ float s[16 * 129];
    const int b = blockIdx.x;
    const int t = threadIdx.x;
    if (b < 192) {
        const int wid = b * 4 + (t >> 6);
        const int lane = t & 63;
        const float *wrow, *as, *an;
        if (wid < 256) {
            wrow = W0 + (size_t)wid * 128;
            int h = wid >> 7;
            as = as0 + h * 128; an = an0 + h * 128;
        } else {
            int g = wid - 256;
            wrow = W1 + (size_t)g * 128;
            int h = g >> 8;
            as = as1 + h * 128; an = an1 + h * 128;
        }
        float2 w = *(const float2*)(wrow + 2 * lane);
        float2 sv = *(const float2*)(as + 2 * lane);
        float2 nv = *(const float2*)(an + 2 * lane);
        float au = sum64(w.x * sv.x + w.y * sv.y);
        float av = sum64(w.x * nv.x + w.y * nv.y);
        if (lane == 0) {
            if (wid < 256) { ws[OFF_UV0 + wid] = au; ws[OFF_UV0 + 256 + wid] = av; }
            else { int g = wid - 256; ws[OFF_U1 + g] = au; ws[OFF_V1 + g] = av; }
        }
    } else {
        const int idx = b - 192;
        const int h = idx >> 4, g0 = (idx & 15) * 16;
        const float* Wh = W1 + (size_t)h * 32768;
        for (int ii = t * 4; ii < 16 * 128; ii += 1024) {
            int i = ii >> 7, d = ii & 127;
            float4 g4 = *(const float4*)(Wh + (size_t)(g0 + i) * 128 + d);
            s[i * 129 + d + 0] = g4.x;
            s[i * 129 + d + 1] = g4.y;
            s[i * 129 + d + 2] = g4.z;
            s[i * 129 + d + 3] = g4.w;
        }
        __syncthreads();
        const int dg = t & 31, rg = t >> 5;
        float4 acc[2];
        acc[0] = make_float4(0.f, 0.f, 0.f, 0.f);
        acc[1] = make_float4(0.f, 0.f, 0.f, 0.f);
        const float* fp = fcW + (size_t)h * 16384 + 4 * dg;
        #pragma unroll 4
        for (int d2 = 0; d2 < 128; ++d2) {
            float4 f4 = *(const float4*)(fp + (size_t)d2 * 128);
            #pragma unroll
            for (int j = 0; j < 2; ++j) {
                float x = s[(rg * 2 + j) * 129 + d2];
                acc[j].x += x * f4.x; acc[j].y += x * f4.y;
                acc[j].z += x * f4.z; acc[j].w += x * f4.w;
            }
        }
        float* Qp = ws + OFF_Q + (size_t)h * 32768;
        #pragma unroll
        for (int j = 0; j < 2; ++j)
            *(float4*)(Qp + (size_t)(g0 + rg * 2 + j) * 128 + 4 * dg) = acc[j];
    }
}

// online-softmax updates
__device__ __forceinline__ void upd2(float& m, float& s, float4& A,
                                     float ea, float eb,
                                     const float4& xa, const float4& xb) {
    float mn = fmaxf(m, fmaxf(ea, eb));
    float sc = __expf(m - mn);
    float pa = __expf(ea - mn);
    float pb = __expf(eb - mn);
    s = s * sc + pa + pb;
    A.x = A.x * sc + pa * xa.x + pb * xb.x;
    A.y = A.y * sc + pa * xa.y + pb * xb.y;
    A.z = A.z * sc + pa * xa.z + pb * xb.z;
    A.w = A.w * sc + pa * xa.w + pb * xb.w;
    m = mn;
}
__device__ __forceinline__ void upd1(float& m, float& s, float4& A,
                                     float ea, const float4& xa) {
    float mn = fmaxf(m, ea);
    float sc = __expf(m - mn);
    float pa = __expf(ea - mn);
    s = s * sc + pa;
    A.x = A.x * sc + pa * xa.x;
    A.y = A.y * sc + pa * xa.y;
    A.z = A.z * sc + pa * xa.z;
    A.w = A.w * sc + pa * xa.w;
    m = mn;
}

// ============ big4: TWO targets per wave (unchanged R9) ============
__global__ __launch_bounds__(256)
void big4_kernel(const float* __restrict__ h0, const float* __restrict__ h1,
                 const float* __restrict__ h2, const float* __restrict__ W0,
                 float* __restrict__ ws) {
    const int b = blockIdx.x;
    const int t = threadIdx.x;
    const float* uv0 = ws + OFF_UV0;

    if (b < 1280) {
        const int lane = t & 63;
        const int sub = lane >> 5;
        const int fl = lane & 31;
        const int m = (b * 4 + (t >> 6)) * 2 + sub;
        const float* xnp = h2 + (size_t)m * 3200;
        const float* xsp = h1 + (size_t)m * 128;
        const float4 u0 = *(const float4*)(uv0 + 0 + 4 * fl);
        const float4 u1 = *(const float4*)(uv0 + 128 + 4 * fl);
        const float4 v0 = *(const float4*)(uv0 + 256 + 4 * fl);
        const float4 v1 = *(const float4*)(uv0 + 384 + 4 * fl);

        float4 xs = *(const float4*)(xsp + 4 * fl);
        const float es0 = sum32(dot4(xs, u0));
        const float es1 = sum32(dot4(xs, u1));

        float4 xa = *(const float4*)(xnp + 4 * fl);
        float4 xb = *(const float4*)(xnp + 128 + 4 * fl);
        float m0 = -1e30f, m1 = -1e30f, s0 = 0.f, s1 = 0.f;
        float4 A0 = make_float4(0.f, 0.f, 0.f, 0.f);
        float4 A1 = make_float4(0.f, 0.f, 0.f, 0.f);
        #pragma unroll
        for (int c = 0; c < 12; ++c) {
            float4 na, nb;
            if (c < 11) {
                na = *(const float4*)(xnp + (size_t)(2 * c + 2) * 128 + 4 * fl);
                nb = *(const float4*)(xnp + (size_t)(2 * c + 3) * 128 + 4 * fl);
            } else {
                na = *(const float4*)(xnp + (size_t)24 * 128 + 4 * fl);
                nb = na;
            }
            float ea0 = lrelu(es0 + sum32(dot4(xa, v0)));
            float ea1 = lrelu(es1 + sum32(dot4(xa, v1)));
            float eb0 = lrelu(es0 + sum32(dot4(xb, v0)));
            float eb1 = lrelu(es1 + sum32(dot4(xb, v1)));
            upd2(m0, s0, A0, ea0, eb0, xa, xb);
            upd2(m1, s1, A1, ea1, eb1, xa, xb);
            xa = na; xb = nb;
        }
        {
            float e0 = lrelu(es0 + sum32(dot4(xa, v0)));
            float e1 = lrelu(es1 + sum32(dot4(xa, v1)));
            upd1(m0, s0, A0, e0, xa);
            upd1(m1, s1, A1, e1, xa);
        }
        const float i0 = 1.f / s0, i1 = 1.f / s1;
        float4 o0, o1;
        o0.x = A0.x * i0; o0.y = A0.y * i0; o0.z = A0.z * i0; o0.w = A0.w * i0;
        o1.x = A1.x * i1; o1.y = A1.y * i1; o1.z = A1.z * i1; o1.w = A1.w * i1;
        *(float4*)(ws + OFF_Y1 + (size_t)m * 256 + 4 * fl) = o0;
        *(float4*)(ws + OFF_Y1 + (size_t)m * 256 + 128 + 4 * fl) = o1;
    } else if (b < 1408) {
        const int lane = t & 63;
        const int sub = lane >> 5;
        const int fl = lane & 31;
        const int m = ((b - 1280) * 4 + (t >> 6)) * 2 + sub;
        const float* xnp = h1 + (size_t)m * 1280;
        const float* xsp = h0 + (size_t)m * 128;
        const float4 u0 = *(const float4*)(uv0 + 0 + 4 * fl);
        const float4 u1 = *(const float4*)(uv0 + 128 + 4 * fl);
        const float4 v0 = *(const float4*)(uv0 + 256 + 4 * fl);
        const float4 v1 = *(const float4*)(uv0 + 384 + 4 * fl);

        float4 xs = *(const float4*)(xsp + 4 * fl);
        const float es0 = sum32(dot4(xs, u0));
        const float es1 = sum32(dot4(xs, u1));

        float4 xa = *(const float4*)(xnp + 4 * fl);
        float4 xb = *(const float4*)(xnp + 128 + 4 * fl);
        float m0 = -1e30f, m1 = -1e30f, s0 = 0.f, s1 = 0.f;
        float4 A0 = make_float4(0.f, 0.f, 0.f, 0.f);
        float4 A1 = make_float4(0.f, 0.f, 0.f, 0.f);
        #pragma unroll
        for (int c = 0; c < 5; ++c) {
            float4 na, nb;
            if (c < 4) {
                na = *(const float4*)(xnp + (size_t)(2 * c + 2) * 128 + 4 * fl);
                nb = *(const float4*)(xnp + (size_t)(2 * c + 3) * 128 + 4 * fl);
            } else {
                na = xa; nb = xb;
            }
            float ea0 = lrelu(es0 + sum32(dot4(xa, v0)));
            float ea1 = lrelu(es1 + sum32(dot4(xa, v1)));
            float eb0 = lrelu(es0 + sum32(dot4(xb, v0)));
            float eb1 = lrelu(es1 + sum32(dot4(xb, v1)));
            upd2(m0, s0, A0, ea0, eb0, xa, xb);
            upd2(m1, s1, A1, ea1, eb1, xa, xb);
            xa = na; xb = nb;
        }
        const float i0 = 1.f / s0, i1 = 1.f / s1;
        float4 o0, o1;
        o0.x = A0.x * i0; o0.y = A0.y * i0; o0.z = A0.z * i0; o0.w = A0.w * i0;
        o1.x = A1.x * i1; o1.y = A1.y * i1; o1.z = A1.z * i1; o1.w = A1.w * i1;
        *(float4*)(ws + OFF_Y0 + (size_t)m * 256 + 4 * fl) = o0;
        *(float4*)(ws + OFF_Y0 + (size_t)m * 256 + 128 + 4 * fl) = o1;
    } else if (b < 1536) {
        const int wid = (b - 1408) * 4 + (t >> 6);
        const int lane = t & 63;
        const int h = wid >> 8, rest = wid & 255;
        const int h0i = rest >> 7;
        const float* wrow = W0 + (size_t)rest * 128;
        float2 w2 = *(const float2*)(wrow + 2 * lane);
        float2 su = *(const float2*)(ws + OFF_U1 + h * 256 + h0i * 128 + 2 * lane);
        float2 sv = *(const float2*)(ws + OFF_V1 + h * 256 + h0i * 128 + 2 * lane);
        float pu = sum64(w2.x * su.x + w2.y * su.y);
        float pv = sum64(w2.x * sv.x + w2.y * sv.y);
        if (lane == 0) { ws[OFF_PP + wid] = pu; ws[OFF_P + wid] = pv; }
    } else {
        __shared__ float smem[4160];
        const int idx = b - 1536;
        const int h = idx >> 3;
        const int h0i = (idx >> 2) & 1;
        const int f0 = (idx & 3) * 32;
        const float* W0h = W0 + (size_t)h0i * 16384;
        for (int ii = t * 4; ii < 32 * 128; ii += 1024) {
            int i = ii >> 7, d = ii & 127;
            float4 g4 = *(const float4*)(W0h + (size_t)(f0 + i) * 128 + d);
            smem[i * 129 + d + 0] = g4.x;
            smem[i * 129 + d + 1] = g4.y;
            smem[i * 129 + d + 2] = g4.z;
            smem[i * 129 + d + 3] = g4.w;
        }
        __syncthreads();
        const int dg = t & 31, rg = t >> 5;
        float4 acc[4];
        #pragma unroll
        for (int j = 0; j < 4; ++j) acc[j] = make_float4(0.f, 0.f, 0.f, 0.f);
        const float* Qp = ws + OFF_Q + (size_t)h * 32768 + (size_t)h0i * 16384 + 4 * dg;
        #pragma unroll 4
        for (int d = 0; d < 128; ++d) {
            float4 q4 = *(const float4*)(Qp + (size_t)d * 128);
            #pragma unroll
            for (int j = 0; j < 4; ++j) {
                float x = smem[(rg * 4 + j) * 129 + d];
                acc[j].x += x * q4.x; acc[j].y += x * q4.y;
                acc[j].z += x * q4.z; acc[j].w += x * q4.w;
            }
        }
        float* Rp = ws + OFF_R + (size_t)h * 32768 + (size_t)h0i * 16384;
        #pragma unroll
        for (int j = 0; j < 4; ++j)
            *(float4*)(Rp + (size_t)(f0 + rg * 4 + j) * 128 + 4 * dg) = acc[j];
    }
}

// ============ FINAL: 512 threads/block (8 waves); coalesced float2 GEMV ============
__global__ __launch_bounds__(512)
void final_kernel(const float* __restrict__ ws, float* __restrict__ out) {
    __shared__ float xn[22 * 256];
    __shared__ float yb[1024];
    __shared__ float pr[8][2][128];
    __shared__ float en[2][11][2];
    __shared__ float al[2][10][2];
    const int t = threadIdx.x;
    const int m0 = blockIdx.x * 2;
    const int rlane = t & 63;
    const int rg = t >> 6;           // 8 waves
    const float* P  = ws + OFF_P;
    const float* Pp = ws + OFF_PP;
    const float* Y1 = ws + OFF_Y1;
    const float* Y0 = ws + OFF_Y0;
    const float4 su0 = *(const float4*)(Pp + 0 + 4 * rlane);
    const float4 su1 = *(const float4*)(Pp + 256 + 4 * rlane);
    const float4 nv0 = *(const float4*)(P + 0 + 4 * rlane);
    const float4 nv1 = *(const float4*)(P + 256 + 4 * rlane);
    float4 g[3];
    #pragma unroll
    for (int i = 0; i < 3; ++i) {
        int rho = rg + 8 * i;
        if (rho < 22) {
            int r = rho / 11, k = rho % 11;
            int m = m0 + r;
            const float* src = (k < 10) ? (Y1 + ((size_t)m * 10 + k) * 256)
                                        : (Y0 + (size_t)m * 256);
            g[i] = *(const float4*)(src + 4 * rlane);
        }
    }
    #pragma unroll
    for (int i = 0; i < 3; ++i) {
        int rho = rg + 8 * i;
        if (rho < 22) {
            int r = rho / 11, k = rho % 11;
            *(float4*)(&xn[rho * 256 + 4 * rlane]) = g[i];
            float p0 = sum64(dot4(g[i], (k < 10) ? nv0 : su0));
            float p1 = sum64(dot4(g[i], (k < 10) ? nv1 : su1));
            if (rlane == 0) { en[r][k][0] = p0; en[r][k][1] = p1; }
        }
    }
    __syncthreads();
    if (t < 128) {
        int r = t >> 6, h = (t >> 5) & 1, k = t & 31;
        float e = -1e30f;
        if (k < 10) {
            float z = en[r][10][h] + en[r][k][h];
            e = (z >= 0.f) ? z : LRELU_SLOPE * z;
        }
        float mx = e;
        #pragma unroll
        for (int off = 16; off > 0; off >>= 1) mx = fmaxf(mx, __shfl_xor(mx, off));
        float ex = (k < 10) ? __expf(e - mx) : 0.f;
        float sm = ex;
        #pragma unroll
        for (int off = 16; off > 0; off >>= 1) sm += __shfl_xor(sm, off);
        if (k < 10) al[r][k][h] = ex / sm;
    }
    __syncthreads();
    #pragma unroll
    for (int i = 0; i < 2; ++i) {
        int c = t + 512 * i;             // [0,1024): [r][h][f]
        int r = c >> 9, rem = c & 511, h = rem >> 8, f = rem & 255;
        float acc = 0.f;
        #pragma unroll
        for (int k = 0; k < 10; ++k) acc += al[r][k][h] * xn[(r * 11 + k) * 256 + f];
        yb[c] = acc;
    }
    __syncthreads();
    // GEMV: 8 gi-segments of 64; each thread owns an o-pair; float2 R loads.
    {
        const int seg = t >> 6;          // [0,8)
        const int op = (t & 63) * 2;     // o pair base
        const float* Rv = ws + OFF_R + (size_t)seg * 64 * 128 + op;
        const float* y0p = yb + seg * 64;
        const float* y1p = yb + 512 + seg * 64;
        float2 a0 = make_float2(0.f, 0.f), a1 = make_float2(0.f, 0.f);
        #pragma unroll 8
        for (int gi = 0; gi < 64; ++gi) {
            float2 rv = *(const float2*)(Rv + (size_t)gi * 128);
            float ya = y0p[gi], yc = y1p[gi];
            a0.x += ya * rv.x; a0.y += ya * rv.y;
            a1.x += yc * rv.x; a1.y += yc * rv.y;
        }
        pr[seg][0][op] = a0.x; pr[seg][0][op + 1] = a0.y;
        pr[seg][1][op] = a1.x; pr[seg][1][op + 1] = a1.y;
    }
    __syncthreads();
    if (t < 256) {
        const int r = t >> 7, o = t & 127;
        float acc = 0.f;
        #pragma unroll
        for (int s = 0; s < 8; ++s) acc += pr[s][r][o];
        out[(size_t)(m0 + r) * 128 + o] = acc;
    }
}

extern "C" void kernel_launch(void* const* d_in, const int* in_sizes, int n_in,
                              void* d_out, int out_size, void* d_ws, size_t ws_size,
                              hipStream_t stream) {
    const float* h0  = (const float*)d_in[0];
    const float* h1  = (const float*)d_in[1];
    const float* h2  = (const float*)d_in[2];
    const float* W0  = (const float*)d_in[3];
    const float* as0 = (const float*)d_in[4];
    const float* an0 = (const float*)d_in[5];
    const float* W1  = (const float*)d_in[6];
    const float* as1 = (const float*)d_in[7];
    const float* an1 = (const float*)d_in[8];
    const float* fcW = (const float*)d_in[9];
    float* outp = (float*)d_out;
    float* ws = (float*)d_ws;

    hipLaunchKernelGGL(prepA_kernel, dim3(224), dim3(256), 0, stream,
                       W0, as0, an0, W1, as1, an1, fcW, ws);
    hipLaunchKernelGGL(big4_kernel, dim3(1552), dim3(256), 0, stream,
                       h0, h1, h2, W0, ws);
    hipLaunchKernelGGL(final_kernel, dim3(512), dim3(512), 0, stream,
                       ws, outp);
}